// Round 1
// baseline (367.514 us; speedup 1.0000x reference)
//
#include <hip/hip_runtime.h>
#include <math.h>

#define DD 2048   // hidden dim
#define EE 16     // experts
#define RR 16     // lora rank
#define QO 2048   // q out dim
#define VO 512    // v out dim
#define TILE 128  // tokens per expert-kernel tile
#define BATCH 16  // tokens per inner batch
#define DC 128    // D-chunk staged in LDS
#define HSTR (DC + 4)  // hs row stride (pad -> only free 2-way conflicts)
#define ASTR 20        // a-tile row stride (16 + 4 pad, keeps float4 alignment)

struct Route { int i0, i1; float w0, w1; };

// ---------------- Kernel 1: router (top-2 softmax weights) + output zero-fill
__global__ __launch_bounds__(256) void router_kernel(
    const float* __restrict__ h, const float* __restrict__ rw,
    Route* __restrict__ route, float4* __restrict__ outz, long long n_f4, int n)
{
    // grid-stride zero of d_out (harness poisons it with 0xAA before every call)
    for (long long i = (long long)blockIdx.x * 256 + threadIdx.x; i < n_f4;
         i += (long long)gridDim.x * 256)
        outz[i] = make_float4(0.f, 0.f, 0.f, 0.f);

    __shared__ float  sh[8 * DD];       // 8 tokens of h, 64 KB
    __shared__ double slogd[8 * EE];

    int t0 = blockIdx.x * 8;
    for (int i = threadIdx.x; i < 8 * DD; i += 256) {
        int tok = t0 + (i >> 11);
        sh[i] = (tok < n) ? h[(size_t)tok * DD + (i & (DD - 1))] : 0.f;
    }
    __syncthreads();

    // 16 lanes per expert; fp64 accumulation for tie-robust top-2
    int e      = threadIdx.x >> 4;
    int lane16 = threadIdx.x & 15;
    double acc[8];
#pragma unroll
    for (int t = 0; t < 8; ++t) acc[t] = 0.0;
    const float* rwe = rw + e * DD;
    for (int d = lane16; d < DD; d += 16) {
        double r = (double)rwe[d];
#pragma unroll
        for (int t = 0; t < 8; ++t) acc[t] += (double)sh[t * DD + d] * r;
    }
#pragma unroll
    for (int t = 0; t < 8; ++t) {
#pragma unroll
        for (int off = 8; off; off >>= 1)
            acc[t] += __shfl_down(acc[t], off, 16);
    }
    if (lane16 == 0) {
#pragma unroll
        for (int t = 0; t < 8; ++t) slogd[t * EE + e] = acc[t];
    }
    __syncthreads();

    if (threadIdx.x < 8) {
        int t = threadIdx.x, tok = t0 + t;
        if (tok < n) {
            double l[EE];
#pragma unroll
            for (int i = 0; i < EE; ++i) l[i] = slogd[t * EE + i];
            // top-2 by value, lower index wins ties (matches jax.lax.top_k)
            int i0 = 0;
            for (int i = 1; i < EE; ++i) if (l[i] > l[i0]) i0 = i;
            int i1 = -1;
            for (int i = 0; i < EE; ++i)
                if (i != i0 && (i1 < 0 || l[i] > l[i1])) i1 = i;
            double mx = l[i0], Z = 0.0;
            for (int i = 0; i < EE; ++i) Z += exp(l[i] - mx);
            double p0 = 1.0 / Z;            // exp(0)/Z
            double p1 = exp(l[i1] - mx) / Z;
            double s  = p0 + p1 + 1e-20;    // reference EPS on score sum
            Route rt;
            rt.i0 = i0; rt.i1 = i1;
            rt.w0 = (float)(2.0 * p0 / s);  // scale = ALPHA/R = 2
            rt.w1 = (float)(2.0 * p1 / s);
            route[tok] = rt;
        }
    }
}

// ---------------- Kernel 2: per-(expert, token-tile) lora A-side + B-side
__global__ __launch_bounds__(256) void expert_kernel(
    const float* __restrict__ h, const Route* __restrict__ route,
    const float* __restrict__ qa, const float* __restrict__ qb,
    const float* __restrict__ va, const float* __restrict__ vb,
    float* __restrict__ outq, float* __restrict__ outv, int n)
{
    int e  = blockIdx.x;
    int t0 = blockIdx.y * TILE;

    __shared__ int   sel_tok[TILE];
    __shared__ float sel_w[TILE];
    __shared__ int   sm_cnt;
    if (threadIdx.x == 0) sm_cnt = 0;
    __syncthreads();
    for (int i = threadIdx.x; i < TILE; i += 256) {
        int tok = t0 + i;
        if (tok < n) {
            Route rt = route[tok];
            float w = 0.f; int sel = 0;
            if      (rt.i0 == e) { sel = 1; w = rt.w0; }
            else if (rt.i1 == e) { sel = 1; w = rt.w1; }
            if (sel) { int p = atomicAdd(&sm_cnt, 1); sel_tok[p] = tok; sel_w[p] = w; }
        }
    }
    __syncthreads();
    int m = sm_cnt;
    if (m == 0) return;

    __align__(16) __shared__ float aq_s[DC * ASTR];   // a_q chunk [d][r], padded
    __align__(16) __shared__ float av_s[DC * ASTR];
    __shared__ float hs[BATCH * HSTR];                // h chunk [tok][d]
    __shared__ float qlow_s[BATCH * RR];
    __shared__ float vlow_s[BATCH * RR];

    const float* qa_e = qa + (size_t)e * DD * RR;
    const float* va_e = va + (size_t)e * DD * RR;
    const float* qb_e = qb + (size_t)e * RR * QO;
    const float* vb_e = vb + (size_t)e * RR * VO;

    // A-side thread mapping: s = d-slice (16), tile -> (tp: token grp, rp: rank grp)
    int s    = threadIdx.x & 15;
    int tile = threadIdx.x >> 4;
    int tp   = tile >> 2;
    int rp   = tile & 3;

    for (int b0 = 0; b0 < m; b0 += BATCH) {
        int mb = min(BATCH, m - b0);

        float accq[4][4], accv[4][4];
#pragma unroll
        for (int ti = 0; ti < 4; ++ti)
#pragma unroll
            for (int ri = 0; ri < 4; ++ri) { accq[ti][ri] = 0.f; accv[ti][ri] = 0.f; }

        for (int d0 = 0; d0 < DD; d0 += DC) {
            __syncthreads();
            for (int i = threadIdx.x; i < DC * RR; i += 256) {
                int d = i >> 4, r = i & 15;
                aq_s[d * ASTR + r] = qa_e[(size_t)(d0 + d) * RR + r];
                av_s[d * ASTR + r] = va_e[(size_t)(d0 + d) * RR + r];
            }
            for (int i = threadIdx.x; i < BATCH * DC; i += 256) {
                int j = i >> 7, d = i & (DC - 1);
                float v = 0.f;
                if (j < mb) v = h[(size_t)sel_tok[b0 + j] * DD + d0 + d];
                hs[j * HSTR + d] = v;
            }
            __syncthreads();
#pragma unroll
            for (int dd = 0; dd < 8; ++dd) {
                int d = (dd << 4) + s;
                float hv[4];
#pragma unroll
                for (int ti = 0; ti < 4; ++ti)
                    hv[ti] = hs[(tp * 4 + ti) * HSTR + d];
                float4 aqv = *(const float4*)&aq_s[d * ASTR + rp * 4];
                float4 avv = *(const float4*)&av_s[d * ASTR + rp * 4];
                const float* aqp = &aqv.x;
                const float* avp = &avv.x;
#pragma unroll
                for (int ti = 0; ti < 4; ++ti)
#pragma unroll
                    for (int ri = 0; ri < 4; ++ri) {
                        accq[ti][ri] = fmaf(hv[ti], aqp[ri], accq[ti][ri]);
                        accv[ti][ri] = fmaf(hv[ti], avp[ri], accv[ti][ri]);
                    }
            }
        }
        // reduce over the 16 d-slices (lanes of each width-16 subgroup)
#pragma unroll
        for (int ti = 0; ti < 4; ++ti)
#pragma unroll
            for (int ri = 0; ri < 4; ++ri) {
#pragma unroll
                for (int off = 8; off; off >>= 1) {
                    accq[ti][ri] += __shfl_down(accq[ti][ri], off, 16);
                    accv[ti][ri] += __shfl_down(accv[ti][ri], off, 16);
                }
            }
        if (s == 0) {
#pragma unroll
            for (int ti = 0; ti < 4; ++ti) {
                int t = tp * 4 + ti;
                float w = (t < mb) ? sel_w[b0 + t] : 0.f;
#pragma unroll
                for (int ri = 0; ri < 4; ++ri) {
                    qlow_s[t * RR + rp * 4 + ri] = accq[ti][ri] * w;
                    vlow_s[t * RR + rp * 4 + ri] = accv[ti][ri] * w;
                }
            }
        }
        __syncthreads();

        // B-side: stream b columns into registers once, reuse for all mb tokens
        for (int q0 = 0; q0 < QO; q0 += 256) {
            int q = q0 + threadIdx.x;
            float bcol[RR];
#pragma unroll
            for (int r = 0; r < RR; ++r) bcol[r] = qb_e[r * QO + q];
            for (int j = 0; j < mb; ++j) {
                float sacc = 0.f;
#pragma unroll
                for (int r = 0; r < RR; ++r)
                    sacc = fmaf(qlow_s[j * RR + r], bcol[r], sacc);
                atomicAdd(outq + (size_t)sel_tok[b0 + j] * QO + q, sacc);
            }
        }
        for (int v0 = 0; v0 < VO; v0 += 256) {
            int vv = v0 + threadIdx.x;
            float bcol[RR];
#pragma unroll
            for (int r = 0; r < RR; ++r) bcol[r] = vb_e[r * VO + vv];
            for (int j = 0; j < mb; ++j) {
                float sacc = 0.f;
#pragma unroll
                for (int r = 0; r < RR; ++r)
                    sacc = fmaf(vlow_s[j * RR + r], bcol[r], sacc);
                atomicAdd(outv + (size_t)sel_tok[b0 + j] * VO + vv, sacc);
            }
        }
        __syncthreads();  // qlow_s / hs / a-tiles reused by next batch
    }
}

extern "C" void kernel_launch(void* const* d_in, const int* in_sizes, int n_in,
                              void* d_out, int out_size, void* d_ws, size_t ws_size,
                              hipStream_t stream) {
    const float* h  = (const float*)d_in[0];
    const float* rw = (const float*)d_in[1];
    const float* qa = (const float*)d_in[2];
    const float* qb = (const float*)d_in[3];
    const float* va = (const float*)d_in[4];
    const float* vb = (const float*)d_in[5];

    int n = in_sizes[0] / DD;           // B*S tokens
    float* out  = (float*)d_out;
    float* outq = out;
    float* outv = out + (size_t)n * QO;
    Route* route = (Route*)d_ws;        // n * 16 bytes

    long long n_f4 = (long long)out_size / 4;  // out_size divisible by 4
    int nb1 = (n + 7) / 8;
    router_kernel<<<nb1, 256, 0, stream>>>(h, rw, route, (float4*)d_out, n_f4, n);

    dim3 g2(EE, (n + TILE - 1) / TILE);
    expert_kernel<<<g2, 256, 0, stream>>>(h, route, qa, qb, va, vb, outq, outv, n);
}

// Round 2
// 261.945 us; speedup vs baseline: 1.4030x; 1.4030x over previous
//
#include <hip/hip_runtime.h>
#include <math.h>

#define DD 2048   // hidden dim
#define EE 16     // experts
#define RR 16     // lora rank
#define QO 2048   // q out dim
#define VO 512    // v out dim
#define TILE 128  // tokens per tile
#define BATCH 16  // tokens per inner batch (A-side)
#define DSPLIT 4  // D-dimension splits for A-side grid
#define DRANGE (DD / DSPLIT)   // 512
#define DC 128    // D-chunk staged in LDS
#define HSTR (DC + 4)  // hs row stride (132, mult of 4 for float4 stores)
#define ASTR 20        // a-tile row stride (16 + 4 pad, float4-aligned)
#define RDC 256        // router D-chunk

struct Route { int i0, i1; float w0, w1; };

// ---------------- K1: router (fp64 logits -> top-2 weights) ----------------
__global__ __launch_bounds__(256) void router_kernel(
    const float* __restrict__ h, const float* __restrict__ rw,
    Route* __restrict__ route, int n)
{
    __shared__ float  hs[8 * RDC];       // 8 KB
    __shared__ double slogd[8 * EE];

    int t0 = blockIdx.x * 8;
    int e  = threadIdx.x >> 4;
    int l  = threadIdx.x & 15;

    double acc[8];
#pragma unroll
    for (int t = 0; t < 8; ++t) acc[t] = 0.0;

    for (int d0 = 0; d0 < DD; d0 += RDC) {
        __syncthreads();
        for (int i = threadIdx.x; i < 8 * (RDC / 4); i += 256) {
            int t = i / (RDC / 4), dq = (i % (RDC / 4)) * 4;
            float4 v = make_float4(0.f, 0.f, 0.f, 0.f);
            if (t0 + t < n)
                v = *(const float4*)&h[(size_t)(t0 + t) * DD + d0 + dq];
            *(float4*)&hs[t * RDC + dq] = v;
        }
        __syncthreads();
        const float* rwe = rw + e * DD + d0;
        for (int d = l; d < RDC; d += 16) {
            double r = (double)rwe[d];
#pragma unroll
            for (int t = 0; t < 8; ++t) acc[t] += (double)hs[t * RDC + d] * r;
        }
    }
#pragma unroll
    for (int t = 0; t < 8; ++t) {
#pragma unroll
        for (int off = 8; off; off >>= 1)
            acc[t] += __shfl_down(acc[t], off, 16);
    }
    if (l == 0) {
#pragma unroll
        for (int t = 0; t < 8; ++t) slogd[t * EE + e] = acc[t];
    }
    __syncthreads();

    if (threadIdx.x < 8) {
        int t = threadIdx.x, tok = t0 + t;
        if (tok < n) {
            double lg[EE];
#pragma unroll
            for (int i = 0; i < EE; ++i) lg[i] = slogd[t * EE + i];
            int i0 = 0;
            for (int i = 1; i < EE; ++i) if (lg[i] > lg[i0]) i0 = i;
            int i1 = -1;
            for (int i = 0; i < EE; ++i)
                if (i != i0 && (i1 < 0 || lg[i] > lg[i1])) i1 = i;
            double mx = lg[i0], Z = 0.0;
            for (int i = 0; i < EE; ++i) Z += exp(lg[i] - mx);
            double p0 = 1.0 / Z;
            double p1 = exp(lg[i1] - mx) / Z;
            double s  = p0 + p1 + 1e-20;
            Route rt;
            rt.i0 = i0; rt.i1 = i1;
            rt.w0 = (float)(2.0 * p0 / s);   // scale = ALPHA/R = 2
            rt.w1 = (float)(2.0 * p1 / s);
            route[tok] = rt;
        }
    }
}

// ---------------- K2: A-side partials + output zero-fill ----------------
// grid (EE, tiles, DSPLIT). Writes low[(tok*2+k)*DSPLIT + ds][32] (w applied).
__global__ __launch_bounds__(256) void a_kernel(
    const float* __restrict__ h, const Route* __restrict__ route,
    const float* __restrict__ qa, const float* __restrict__ va,
    float* __restrict__ low, float4* __restrict__ outz, long long n_f4, int n)
{
    // high-occupancy zero of d_out (K3's atomics start only after K2 completes)
    long long nb  = (long long)EE * gridDim.y * DSPLIT;
    long long bid = blockIdx.x + (long long)EE * (blockIdx.y + (long long)gridDim.y * blockIdx.z);
    for (long long i = bid * 256 + threadIdx.x; i < n_f4; i += nb * 256)
        outz[i] = make_float4(0.f, 0.f, 0.f, 0.f);

    int e  = blockIdx.x;
    int t0 = blockIdx.y * TILE;
    int ds = blockIdx.z;

    __shared__ int   sel_tok[TILE];
    __shared__ float sel_w[TILE];
    __shared__ int   sel_k[TILE];
    __shared__ int   sm_cnt;
    if (threadIdx.x == 0) sm_cnt = 0;
    __syncthreads();
    for (int i = threadIdx.x; i < TILE; i += 256) {
        int tok = t0 + i;
        if (tok < n) {
            Route rt = route[tok];
            float w = 0.f; int sel = 0, k = 0;
            if      (rt.i0 == e) { sel = 1; w = rt.w0; k = 0; }
            else if (rt.i1 == e) { sel = 1; w = rt.w1; k = 1; }
            if (sel) {
                int p = atomicAdd(&sm_cnt, 1);
                sel_tok[p] = tok; sel_w[p] = w; sel_k[p] = k;
            }
        }
    }
    __syncthreads();
    int m = sm_cnt;
    if (m == 0) return;

    __align__(16) __shared__ float aq_s[DC * ASTR];
    __align__(16) __shared__ float av_s[DC * ASTR];
    __align__(16) __shared__ float hs[BATCH * HSTR];

    const float* qa_e = qa + (size_t)e * DD * RR;
    const float* va_e = va + (size_t)e * DD * RR;

    int s    = threadIdx.x & 15;   // d-slice
    int tile = threadIdx.x >> 4;
    int tp   = tile >> 2;          // token group
    int rp   = tile & 3;           // rank group

    for (int b0 = 0; b0 < m; b0 += BATCH) {
        int mb = min(BATCH, m - b0);

        float accq[4][4], accv[4][4];
#pragma unroll
        for (int ti = 0; ti < 4; ++ti)
#pragma unroll
            for (int ri = 0; ri < 4; ++ri) { accq[ti][ri] = 0.f; accv[ti][ri] = 0.f; }

        for (int d0 = ds * DRANGE; d0 < (ds + 1) * DRANGE; d0 += DC) {
            __syncthreads();
            // stage a tiles (float4)
            for (int i = threadIdx.x; i < DC * RR / 4; i += 256) {
                int d = i >> 2, rf = (i & 3) * 4;
                *(float4*)&aq_s[d * ASTR + rf] = *(const float4*)&qa_e[(size_t)(d0 + d) * RR + rf];
                *(float4*)&av_s[d * ASTR + rf] = *(const float4*)&va_e[(size_t)(d0 + d) * RR + rf];
            }
            // stage h chunk (float4)
            for (int i = threadIdx.x; i < BATCH * DC / 4; i += 256) {
                int j = i >> 5, dq = (i & 31) * 4;
                float4 v = make_float4(0.f, 0.f, 0.f, 0.f);
                if (j < mb)
                    v = *(const float4*)&h[(size_t)sel_tok[b0 + j] * DD + d0 + dq];
                *(float4*)&hs[j * HSTR + dq] = v;
            }
            __syncthreads();
#pragma unroll
            for (int dd = 0; dd < 8; ++dd) {
                int d = (dd << 4) + s;
                float hv[4];
#pragma unroll
                for (int ti = 0; ti < 4; ++ti)
                    hv[ti] = hs[(tp * 4 + ti) * HSTR + d];
                float4 aqv = *(const float4*)&aq_s[d * ASTR + rp * 4];
                float4 avv = *(const float4*)&av_s[d * ASTR + rp * 4];
                const float* aqp = &aqv.x;
                const float* avp = &avv.x;
#pragma unroll
                for (int ti = 0; ti < 4; ++ti)
#pragma unroll
                    for (int ri = 0; ri < 4; ++ri) {
                        accq[ti][ri] = fmaf(hv[ti], aqp[ri], accq[ti][ri]);
                        accv[ti][ri] = fmaf(hv[ti], avp[ri], accv[ti][ri]);
                    }
            }
        }
#pragma unroll
        for (int ti = 0; ti < 4; ++ti)
#pragma unroll
            for (int ri = 0; ri < 4; ++ri) {
#pragma unroll
                for (int off = 8; off; off >>= 1) {
                    accq[ti][ri] += __shfl_down(accq[ti][ri], off, 16);
                    accv[ti][ri] += __shfl_down(accv[ti][ri], off, 16);
                }
            }
        if (s == 0) {
#pragma unroll
            for (int ti = 0; ti < 4; ++ti) {
                int t = tp * 4 + ti;
                if (t < mb) {
                    int   tok = sel_tok[b0 + t];
                    int   k   = sel_k[b0 + t];
                    float w   = sel_w[b0 + t];
                    size_t base = ((size_t)(tok * 2 + k) * DSPLIT + ds) * 32;
#pragma unroll
                    for (int ri = 0; ri < 4; ++ri) {
                        low[base + rp * 4 + ri]      = accq[ti][ri] * w;
                        low[base + 16 + rp * 4 + ri] = accv[ti][ri] * w;
                    }
                }
            }
        }
        __syncthreads();
    }
}

// ---------------- K3: B-side, grid (EE, tiles, 5 col-groups) ----------------
__global__ __launch_bounds__(256) void b_kernel(
    const Route* __restrict__ route, const float* __restrict__ low,
    const float* __restrict__ qb, const float* __restrict__ vb,
    float* __restrict__ outq, float* __restrict__ outv, int n)
{
    int e  = blockIdx.x;
    int t0 = blockIdx.y * TILE;
    int cg = blockIdx.z;               // 0..3 -> q cols, 4 -> v cols

    __shared__ int sel_tok[TILE];
    __shared__ int sel_k[TILE];
    __shared__ int sm_cnt;
    if (threadIdx.x == 0) sm_cnt = 0;
    __syncthreads();
    for (int i = threadIdx.x; i < TILE; i += 256) {
        int tok = t0 + i;
        if (tok < n) {
            Route rt = route[tok];
            int sel = 0, k = 0;
            if      (rt.i0 == e) { sel = 1; k = 0; }
            else if (rt.i1 == e) { sel = 1; k = 1; }
            if (sel) {
                int p = atomicAdd(&sm_cnt, 1);
                sel_tok[p] = tok; sel_k[p] = k;
            }
        }
    }
    __syncthreads();
    int m = sm_cnt;
    if (m == 0) return;

    int side = (cg == 4) ? 1 : 0;

    __shared__ float ls[TILE * RR];    // 8 KB worst case
    for (int i = threadIdx.x; i < m * RR; i += 256) {
        int j = i >> 4, r = i & 15;
        size_t base = (size_t)(sel_tok[j] * 2 + sel_k[j]) * DSPLIT * 32 + side * 16 + r;
        ls[j * RR + r] = low[base] + low[base + 32] + low[base + 64] + low[base + 96];
    }
    __syncthreads();

    const float* bp;
    float* outp;
    int W, colbase;
    if (cg < 4) { bp = qb + (size_t)e * RR * QO; outp = outq; W = QO; colbase = cg * 512; }
    else        { bp = vb + (size_t)e * RR * VO; outp = outv; W = VO; colbase = 0; }

#pragma unroll
    for (int g = 0; g < 2; ++g) {
        int col = colbase + g * 256 + threadIdx.x;
        float bcol[RR];
#pragma unroll
        for (int r = 0; r < RR; ++r) bcol[r] = bp[(size_t)r * W + col];
        for (int j = 0; j < m; ++j) {
            float acc = 0.f;
#pragma unroll
            for (int r = 0; r < RR; ++r)
                acc = fmaf(ls[j * RR + r], bcol[r], acc);
            atomicAdd(outp + (size_t)sel_tok[j] * W + col, acc);
        }
    }
}

extern "C" void kernel_launch(void* const* d_in, const int* in_sizes, int n_in,
                              void* d_out, int out_size, void* d_ws, size_t ws_size,
                              hipStream_t stream) {
    const float* h  = (const float*)d_in[0];
    const float* rw = (const float*)d_in[1];
    const float* qa = (const float*)d_in[2];
    const float* qb = (const float*)d_in[3];
    const float* va = (const float*)d_in[4];
    const float* vb = (const float*)d_in[5];

    int n = in_sizes[0] / DD;
    float* out  = (float*)d_out;
    float* outq = out;
    float* outv = out + (size_t)n * QO;

    Route* route = (Route*)d_ws;                               // n*16 B
    float* low   = (float*)((char*)d_ws + ((size_t)n * 16 + 255 & ~(size_t)255));
    // low: n * 2 slots * DSPLIT * 32 floats = 4 MB @ n=4096

    long long n_f4 = (long long)out_size / 4;
    int tiles = (n + TILE - 1) / TILE;

    router_kernel<<<(n + 7) / 8, 256, 0, stream>>>(h, rw, route, n);

    dim3 g2(EE, tiles, DSPLIT);
    a_kernel<<<g2, 256, 0, stream>>>(h, route, qa, va, low, (float4*)d_out, n_f4, n);

    dim3 g3(EE, tiles, 5);
    b_kernel<<<g3, 256, 0, stream>>>(route, low, qb, vb, outq, outv, n);
}

// Round 3
// 221.898 us; speedup vs baseline: 1.6562x; 1.1805x over previous
//
#include <hip/hip_runtime.h>
#include <math.h>

#define DD 2048   // hidden dim
#define EE 16     // experts
#define RR 16     // lora rank
#define QO 2048   // q out dim
#define VO 512    // v out dim
#define TILE 128  // tokens per A-side tile
#define BATCH 16  // tokens per inner batch (A-side)
#define DSPLIT 4  // D splits for A-side grid
#define DRANGE (DD / DSPLIT)   // 512
#define DC 64     // D-chunk staged in LDS (16.4 KB total -> 8 blocks/CU)
#define HSTR (DC + 4)  // 68, mult of 4 for float4
#define ASTR 20        // 16 + 4 pad, float4-aligned
#define RDC 256        // router D-chunk
#define T2 32          // B-side tokens per tile
#define CGQ (QO / 256) // 8 q column groups
#define CGV (VO / 256) // 2 v column groups

struct Route { int i0, i1; float w0, w1; };

// ---------------- K1: router (fp64 logits -> top-2 weights) ----------------
__global__ __launch_bounds__(256) void router_kernel(
    const float* __restrict__ h, const float* __restrict__ rw,
    Route* __restrict__ route, int n)
{
    __shared__ float  hs[8 * RDC];       // 8 KB
    __shared__ double slogd[8 * EE];

    int t0 = blockIdx.x * 8;
    int e  = threadIdx.x >> 4;
    int l  = threadIdx.x & 15;

    double acc[8];
#pragma unroll
    for (int t = 0; t < 8; ++t) acc[t] = 0.0;

    for (int d0 = 0; d0 < DD; d0 += RDC) {
        __syncthreads();
        for (int i = threadIdx.x; i < 8 * (RDC / 4); i += 256) {
            int t = i >> 6, dq = (i & 63) * 4;        // RDC/4 == 64
            float4 v = make_float4(0.f, 0.f, 0.f, 0.f);
            if (t0 + t < n)
                v = *(const float4*)&h[(size_t)(t0 + t) * DD + d0 + dq];
            *(float4*)&hs[t * RDC + dq] = v;
        }
        __syncthreads();
        const float* rwe = rw + e * DD + d0;
#pragma unroll
        for (int g = 0; g < RDC / 64; ++g) {          // 4 passes, lanes cover 64 d
            int d = g * 64 + l * 4;
            float4 r4 = *(const float4*)&rwe[d];
            double rx = r4.x, ry = r4.y, rz = r4.z, rw4 = r4.w;
#pragma unroll
            for (int t = 0; t < 8; ++t) {
                float4 hv = *(const float4*)&hs[t * RDC + d];
                acc[t] += (double)hv.x * rx + (double)hv.y * ry
                        + (double)hv.z * rz + (double)hv.w * rw4;
            }
        }
    }
#pragma unroll
    for (int t = 0; t < 8; ++t) {
#pragma unroll
        for (int off = 8; off; off >>= 1)
            acc[t] += __shfl_down(acc[t], off, 16);
    }
    if (l == 0) {
#pragma unroll
        for (int t = 0; t < 8; ++t) slogd[t * EE + e] = acc[t];
    }
    __syncthreads();

    if (threadIdx.x < 8) {
        int t = threadIdx.x, tok = t0 + t;
        if (tok < n) {
            double lg[EE];
#pragma unroll
            for (int i = 0; i < EE; ++i) lg[i] = slogd[t * EE + i];
            int i0 = 0;
            for (int i = 1; i < EE; ++i) if (lg[i] > lg[i0]) i0 = i;
            int i1 = -1;
            for (int i = 0; i < EE; ++i)
                if (i != i0 && (i1 < 0 || lg[i] > lg[i1])) i1 = i;
            double mx = lg[i0], Z = 0.0;
            for (int i = 0; i < EE; ++i) Z += exp(lg[i] - mx);
            double p0 = 1.0 / Z;
            double p1 = exp(lg[i1] - mx) / Z;
            double s  = p0 + p1 + 1e-20;
            Route rt;
            rt.i0 = i0; rt.i1 = i1;
            rt.w0 = (float)(2.0 * p0 / s);   // scale = ALPHA/R = 2
            rt.w1 = (float)(2.0 * p1 / s);
            route[tok] = rt;
        }
    }
}

// ---------------- K2: A-side partials -> low workspace ----------------
// grid (EE, tiles, DSPLIT). low[(tok*2+k)*DSPLIT*32 + ds*32 + (q:0..15 | v:16..31)]
__global__ __launch_bounds__(256) void a_kernel(
    const float* __restrict__ h, const Route* __restrict__ route,
    const float* __restrict__ qa, const float* __restrict__ va,
    float* __restrict__ low, int n)
{
    int e  = blockIdx.x;
    int t0 = blockIdx.y * TILE;
    int ds = blockIdx.z;

    __shared__ int   sel_tok[TILE];
    __shared__ float sel_w[TILE];
    __shared__ int   sel_k[TILE];
    __shared__ int   sm_cnt;
    if (threadIdx.x == 0) sm_cnt = 0;
    __syncthreads();
    for (int i = threadIdx.x; i < TILE; i += 256) {
        int tok = t0 + i;
        if (tok < n) {
            Route rt = route[tok];
            float w = 0.f; int sel = 0, k = 0;
            if      (rt.i0 == e) { sel = 1; w = rt.w0; k = 0; }
            else if (rt.i1 == e) { sel = 1; w = rt.w1; k = 1; }
            if (sel) {
                int p = atomicAdd(&sm_cnt, 1);
                sel_tok[p] = tok; sel_w[p] = w; sel_k[p] = k;
            }
        }
    }
    __syncthreads();
    int m = sm_cnt;
    if (m == 0) return;

    __align__(16) __shared__ float aq_s[DC * ASTR];   // 5.1 KB
    __align__(16) __shared__ float av_s[DC * ASTR];   // 5.1 KB
    __align__(16) __shared__ float hs[BATCH * HSTR];  // 4.3 KB

    const float* qa_e = qa + (size_t)e * DD * RR;
    const float* va_e = va + (size_t)e * DD * RR;

    int s    = threadIdx.x & 15;   // d-slice
    int tile = threadIdx.x >> 4;
    int tp   = tile >> 2;          // token group
    int rp   = tile & 3;           // rank group

    for (int b0 = 0; b0 < m; b0 += BATCH) {
        int mb = min(BATCH, m - b0);

        float accq[4][4], accv[4][4];
#pragma unroll
        for (int ti = 0; ti < 4; ++ti)
#pragma unroll
            for (int ri = 0; ri < 4; ++ri) { accq[ti][ri] = 0.f; accv[ti][ri] = 0.f; }

        for (int d0 = ds * DRANGE; d0 < (ds + 1) * DRANGE; d0 += DC) {
            __syncthreads();
            {   // stage a tiles: DC*RR/4 == 256 float4 tasks == 1/thread
                int i = threadIdx.x;
                int d = i >> 2, rf = (i & 3) * 4;
                *(float4*)&aq_s[d * ASTR + rf] = *(const float4*)&qa_e[(size_t)(d0 + d) * RR + rf];
                *(float4*)&av_s[d * ASTR + rf] = *(const float4*)&va_e[(size_t)(d0 + d) * RR + rf];
            }
            {   // stage h chunk: BATCH*DC/4 == 256 float4 tasks == 1/thread
                int i = threadIdx.x;
                int j = i >> 4, dq = (i & 15) * 4;
                float4 v = make_float4(0.f, 0.f, 0.f, 0.f);
                if (j < mb)
                    v = *(const float4*)&h[(size_t)sel_tok[b0 + j] * DD + d0 + dq];
                *(float4*)&hs[j * HSTR + dq] = v;
            }
            __syncthreads();
#pragma unroll
            for (int dd = 0; dd < DC / 16; ++dd) {    // 4
                int d = (dd << 4) + s;
                float hv[4];
#pragma unroll
                for (int ti = 0; ti < 4; ++ti)
                    hv[ti] = hs[(tp * 4 + ti) * HSTR + d];
                float4 aqv = *(const float4*)&aq_s[d * ASTR + rp * 4];
                float4 avv = *(const float4*)&av_s[d * ASTR + rp * 4];
                const float* aqp = &aqv.x;
                const float* avp = &avv.x;
#pragma unroll
                for (int ti = 0; ti < 4; ++ti)
#pragma unroll
                    for (int ri = 0; ri < 4; ++ri) {
                        accq[ti][ri] = fmaf(hv[ti], aqp[ri], accq[ti][ri]);
                        accv[ti][ri] = fmaf(hv[ti], avp[ri], accv[ti][ri]);
                    }
            }
        }
#pragma unroll
        for (int ti = 0; ti < 4; ++ti)
#pragma unroll
            for (int ri = 0; ri < 4; ++ri) {
#pragma unroll
                for (int off = 8; off; off >>= 1) {
                    accq[ti][ri] += __shfl_down(accq[ti][ri], off, 16);
                    accv[ti][ri] += __shfl_down(accv[ti][ri], off, 16);
                }
            }
        if (s == 0) {
#pragma unroll
            for (int ti = 0; ti < 4; ++ti) {
                int t = tp * 4 + ti;
                if (t < mb) {
                    int   tok = sel_tok[b0 + t];
                    int   k   = sel_k[b0 + t];
                    float w   = sel_w[b0 + t];
                    size_t base = ((size_t)(tok * 2 + k) * DSPLIT + ds) * 32;
#pragma unroll
                    for (int ri = 0; ri < 4; ++ri) {
                        low[base + rp * 4 + ri]      = accq[ti][ri] * w;
                        low[base + 16 + rp * 4 + ri] = accv[ti][ri] * w;
                    }
                }
            }
        }
        __syncthreads();
    }
}

// ---------------- K3: B-side, token-major, expert-bucketed, no atomics -----
// grid (n/T2, CGQ+CGV). Block owns 32 tokens x 256 cols; LDS acc, one store.
__global__ __launch_bounds__(256) void b_kernel(
    const Route* __restrict__ route, const float* __restrict__ low,
    const float* __restrict__ qb, const float* __restrict__ vb,
    float* __restrict__ outq, float* __restrict__ outv, int n)
{
    int t0 = blockIdx.x * T2;
    int cg = blockIdx.y;               // 0..7 -> q cols, 8..9 -> v cols
    int tid = threadIdx.x;

    __shared__ float acc_s[T2 * 256];  // 32 KB, [token][col-thread]
    __shared__ float ls[T2 * 2 * RR];  // 4 KB, slot-major low vectors
    __shared__ int   elist[EE * T2];   // 2 KB
    __shared__ int   ecnt[EE];
    __shared__ Route rts[T2];

    if (tid < EE) ecnt[tid] = 0;
    if (tid < T2) {
        int tok = t0 + tid;
        if (tok < n) rts[tid] = route[tok];
        else { rts[tid].i0 = -1; rts[tid].i1 = -1; rts[tid].w0 = 0.f; rts[tid].w1 = 0.f; }
    }
    __syncthreads();
    if (tid < T2 * 2) {
        int j = tid >> 1, k = tid & 1;
        int e = k ? rts[j].i1 : rts[j].i0;
        if (e >= 0) {
            int p = atomicAdd(&ecnt[e], 1);
            elist[e * T2 + p] = j * 2 + k;
        }
    }
    int side = (cg >= CGQ) ? 1 : 0;
    {   // stage ls: 64 slots x 4 float4 groups == 256 tasks == 1/thread
        int slot = tid >> 2, r4 = (tid & 3) * 4;
        int j = slot >> 1, k = slot & 1;
        int tok = t0 + j;
        float4 v = make_float4(0.f, 0.f, 0.f, 0.f);
        if (tok < n) {
            const float* lp = low + (size_t)(tok * 2 + k) * (DSPLIT * 32) + side * 16 + r4;
            float4 p0 = *(const float4*)(lp);
            float4 p1 = *(const float4*)(lp + 32);
            float4 p2 = *(const float4*)(lp + 64);
            float4 p3 = *(const float4*)(lp + 96);
            v.x = p0.x + p1.x + p2.x + p3.x;
            v.y = p0.y + p1.y + p2.y + p3.y;
            v.z = p0.z + p1.z + p2.z + p3.z;
            v.w = p0.w + p1.w + p2.w + p3.w;
        }
        *(float4*)&ls[slot * RR + r4] = v;
    }
#pragma unroll
    for (int j = 0; j < T2; ++j) acc_s[j * 256 + tid] = 0.f;
    __syncthreads();

    const float* bp; float* outp; int W, colbase;
    if (cg < CGQ) { bp = qb; outp = outq; W = QO; colbase = cg * 256; }
    else          { bp = vb; outp = outv; W = VO; colbase = (cg - CGQ) * 256; }
    int col = colbase + tid;

    for (int e = 0; e < EE; ++e) {
        int c = ecnt[e];
        if (c == 0) continue;
        const float* be = bp + (size_t)e * RR * W + col;
        float bc[RR];
#pragma unroll
        for (int r = 0; r < RR; ++r) bc[r] = be[(size_t)r * W];
        for (int ii = 0; ii < c; ++ii) {
            int sk = elist[e * T2 + ii];
            int j  = sk >> 1;
            const float* lp = &ls[sk * RR];
            float4 l0 = *(const float4*)(lp);
            float4 l1 = *(const float4*)(lp + 4);
            float4 l2 = *(const float4*)(lp + 8);
            float4 l3 = *(const float4*)(lp + 12);
            float v = 0.f;
            v = fmaf(l0.x, bc[0],  v); v = fmaf(l0.y, bc[1],  v);
            v = fmaf(l0.z, bc[2],  v); v = fmaf(l0.w, bc[3],  v);
            v = fmaf(l1.x, bc[4],  v); v = fmaf(l1.y, bc[5],  v);
            v = fmaf(l1.z, bc[6],  v); v = fmaf(l1.w, bc[7],  v);
            v = fmaf(l2.x, bc[8],  v); v = fmaf(l2.y, bc[9],  v);
            v = fmaf(l2.z, bc[10], v); v = fmaf(l2.w, bc[11], v);
            v = fmaf(l3.x, bc[12], v); v = fmaf(l3.y, bc[13], v);
            v = fmaf(l3.z, bc[14], v); v = fmaf(l3.w, bc[15], v);
            acc_s[j * 256 + tid] += v;   // thread-private column, no race
        }
    }
    // each thread wrote only its own acc column -> no barrier needed
#pragma unroll
    for (int j = 0; j < T2; ++j) {
        int tok = t0 + j;
        if (tok < n) outp[(size_t)tok * W + col] = acc_s[j * 256 + tid];
    }
}

extern "C" void kernel_launch(void* const* d_in, const int* in_sizes, int n_in,
                              void* d_out, int out_size, void* d_ws, size_t ws_size,
                              hipStream_t stream) {
    const float* h  = (const float*)d_in[0];
    const float* rw = (const float*)d_in[1];
    const float* qa = (const float*)d_in[2];
    const float* qb = (const float*)d_in[3];
    const float* va = (const float*)d_in[4];
    const float* vb = (const float*)d_in[5];

    int n = in_sizes[0] / DD;
    float* out  = (float*)d_out;
    float* outq = out;
    float* outv = out + (size_t)n * QO;

    Route* route = (Route*)d_ws;                               // n*16 B
    float* low   = (float*)((char*)d_ws + (((size_t)n * 16 + 255) & ~(size_t)255));
    // low: n * 2 slots * DSPLIT * 32 floats = 4 MB @ n=4096

    int tiles = (n + TILE - 1) / TILE;

    router_kernel<<<(n + 7) / 8, 256, 0, stream>>>(h, rw, route, n);

    dim3 g2(EE, tiles, DSPLIT);
    a_kernel<<<g2, 256, 0, stream>>>(h, route, qa, va, low, n);

    dim3 g3((n + T2 - 1) / T2, CGQ + CGV);
    b_kernel<<<g3, 256, 0, stream>>>(route, low, qb, vb, outq, outv, n);
}